// Round 11
// baseline (158.455 us; speedup 1.0000x reference)
//
#include <hip/hip_runtime.h>
#include <math.h>

#define CC   256   // clusters
#define TILE 128   // points per block; 256 threads, half-split over clusters

// float-index offsets in ws
#define OFF_P     0        // 256 x float4: (twok*mu_x, twok*mu_y, twok*mu_z, alpha)
#define OFF_Q     1024     // 256 x float4: mu_new (unscaled)
#define OFF_S     2048     // S[256] | Ax[256] | Ay[256] | Az[256]
#define OFF_CD    3072     // 4 doubles: [0]=sumX2 [1]=sumT2 [2]=sumY2 [3]=sumSM2new
#define OFF_CF    3080     // floats: [0]=twok [1]=lgn [2]=inv2sn2 [3]=sumSlpi(ln) [4]=sumGL2(log2)
#define OFF_T2    3088     // N floats: per-point log2-normalizer

__device__ __forceinline__ float fexp2(float x) { return __builtin_amdgcn_exp2f(x); }
__device__ __forceinline__ float flog2(float x) { return __builtin_amdgcn_logf(x); }  // v_log_f32 = log2

__global__ __launch_bounds__(256) void gmm_prep(const float* __restrict__ mu,
                                                const float* __restrict__ w,
                                                const float* __restrict__ sigma,
                                                float* __restrict__ ws)
{
    __shared__ float redA[4], redB[4];
    const int c = threadIdx.x;
    const int lane = c & 63, wid = c >> 6;

    // zero per-launch accumulators (stream-ordered before pass1)
    ws[OFF_S + c] = 0.f; ws[OFF_S + 256 + c] = 0.f;
    ws[OFF_S + 512 + c] = 0.f; ws[OFF_S + 768 + c] = 0.f;
    if (c < 4) ((double*)(ws + OFF_CD))[c] = 0.0;
    if (c >= 8 && c < 16) ws[OFF_CF + (c - 6)] = 0.f;

    float wc = w[c];
    // Zw = logsumexp(w) over 256
    float m = wc;
    #pragma unroll
    for (int off = 32; off > 0; off >>= 1) m = fmaxf(m, __shfl_xor(m, off));
    if (lane == 0) redA[wid] = m;
    __syncthreads();
    m = fmaxf(fmaxf(redA[0], redA[1]), fmaxf(redA[2], redA[3]));
    float e = expf(wc - m);
    #pragma unroll
    for (int off = 32; off > 0; off >>= 1) e += __shfl_xor(e, off);
    if (lane == 0) redB[wid] = e;
    __syncthreads();
    float Zw = m + logf(redB[0] + redB[1] + redB[2] + redB[3]);

    const float L = 1.4426950408889634f;   // log2(e)
    float sig = sigma[0];
    float lgn = 3.0f * (logf(sig) + 0.91893853320467274f);  // d*(log sig + 0.5*log 2pi)
    float k = L / (2.0f * sig * sig);
    float twok = 2.0f * k;
    float mx = mu[3*c], my = mu[3*c+1], mz = mu[3*c+2];
    float m2 = mx*mx + my*my + mz*mz;
    float alpha = (wc - Zw - lgn) * L - k * m2;
    // pre-scaled: u_nc = x*P.x + y*P.y + z*P.z + P.w  (pure 3-fma chain)
    ((float4*)(ws + OFF_P))[c] = make_float4(twok*mx, twok*my, twok*mz, alpha);
    if (c == 0) { ws[OFF_CF + 0] = twok; ws[OFF_CF + 1] = lgn; }
}

__global__ __launch_bounds__(256, 4) void gmm_pass1(const float* __restrict__ X,
                                                    float* __restrict__ ws, int N)
{
    __shared__ float4 Psh[CC];
    __shared__ float4 XT[TILE];        // (x,y,z,T2) for phase B
    __shared__ float2 msP[2][TILE];    // per-half (m,s) partials per point
    __shared__ float4 Bpart[CC];       // half1 phase-B partials per cluster
    __shared__ double redd[2][4];

    const int tid  = threadIdx.x;
    const int pi   = tid & 127;
    const int half = tid >> 7;
    const int n0   = blockIdx.x * TILE;
    const int NT   = min(TILE, N - n0);

    Psh[tid] = ((const float4*)(ws + OFF_P))[tid];

    // one register-resident point per thread (each point covered by both halves)
    const bool v0 = pi < NT;
    float x0=0.f, y0=0.f, z0=0.f;
    if (v0) { const float* p = X + 3*(size_t)(n0+pi); x0=p[0]; y0=p[1]; z0=p[2]; }
    float q0 = fmaf(x0,x0, fmaf(y0,y0, z0*z0));
    __syncthreads();   // Psh ready

    // phase A: 1 point x 128 clusters per thread (half-split), chunk-8 deferred max
    const float4* Pc = Psh + half*128;
    float m0 = -3.0e38f, s0 = 0.f;
    for (int c0 = 0; c0 < 128; c0 += 8) {
        float u0[8];
        #pragma unroll
        for (int j = 0; j < 8; ++j) {
            float4 p = Pc[c0 + j];
            u0[j] = fmaf(x0,p.x, fmaf(y0,p.y, fmaf(z0,p.z, p.w)));
        }
        float a = fmaxf(fmaxf(u0[0],u0[1]), fmaxf(u0[2],u0[3]));
        float b = fmaxf(fmaxf(u0[4],u0[5]), fmaxf(u0[6],u0[7]));
        float M = fmaxf(a, b);
        if (__any(M > m0)) {               // at most once per chunk
            M = fmaxf(M, m0);
            s0 *= fexp2(m0 - M);
            m0 = M;
        }
        #pragma unroll
        for (int j = 0; j < 8; ++j) s0 += fexp2(u0[j] - m0);
    }
    msP[half][pi] = make_float2(m0, s0);
    __syncthreads();   // msP ready

    // merge halves -> T2; write XT; accumulate sumX2/sumT2 (half0 only)
    double xd = 0.0, td = 0.0;
    if (half == 0 && v0) {
        float2 a = msP[0][pi], b = msP[1][pi];
        float M = fmaxf(a.x, b.x);
        float T2 = M + flog2(a.y*fexp2(a.x-M) + b.y*fexp2(b.x-M));
        XT[pi] = make_float4(x0,y0,z0,T2);
        ws[OFF_T2 + n0 + pi] = T2;
        xd = (double)q0; td = (double)T2;
    }
    {
        const int lane = tid & 63, wid = tid >> 6;
        #pragma unroll
        for (int off = 32; off > 0; off >>= 1) { xd += __shfl_xor(xd, off); td += __shfl_xor(td, off); }
        if (lane == 0) { redd[0][wid] = xd; redd[1][wid] = td; }
    }
    __syncthreads();   // XT + redd ready
    if (tid == 0) {
        double* CD = (double*)(ws + OFF_CD);
        atomicAdd(CD + 0, redd[0][0]+redd[0][1]+redd[0][2]+redd[0][3]);
        atomicAdd(CD + 1, redd[1][0]+redd[1][1]+redd[1][2]+redd[1][3]);
    }

    // phase B: 2 clusters (pi, pi+128) x 64 points (point-half split)
    float4 pA = Psh[pi], pB = Psh[pi + 128];
    float SA=0.f,AxA=0.f,AyA=0.f,AzA=0.f, SB=0.f,AxB=0.f,AyB=0.f,AzB=0.f;
    const int nlo = half*64, nhi = min(nlo + 64, NT);
    #pragma unroll 8
    for (int n = nlo; n < nhi; ++n) {
        float4 xt = XT[n];
        float uA = fmaf(xt.x,pA.x, fmaf(xt.y,pA.y, fmaf(xt.z,pA.z, pA.w)));
        float uB = fmaf(xt.x,pB.x, fmaf(xt.y,pB.y, fmaf(xt.z,pB.z, pB.w)));
        float gA = fexp2(uA - xt.w);
        float gB = fexp2(uB - xt.w);
        SA+=gA; AxA=fmaf(gA,xt.x,AxA); AyA=fmaf(gA,xt.y,AyA); AzA=fmaf(gA,xt.z,AzA);
        SB+=gB; AxB=fmaf(gB,xt.x,AxB); AyB=fmaf(gB,xt.y,AyB); AzB=fmaf(gB,xt.z,AzB);
    }
    if (half == 1) {
        Bpart[pi]       = make_float4(SA,AxA,AyA,AzA);
        Bpart[pi + 128] = make_float4(SB,AxB,AyB,AzB);
    }
    __syncthreads();   // Bpart ready
    if (half == 0) {
        float4 bA = Bpart[pi], bB = Bpart[pi + 128];
        SA+=bA.x; AxA+=bA.y; AyA+=bA.z; AzA+=bA.w;
        SB+=bB.x; AxB+=bB.y; AyB+=bB.z; AzB+=bB.w;
        float* Sg = ws + OFF_S;
        atomicAdd(Sg       + pi, SA);   atomicAdd(Sg       + pi + 128, SB);
        atomicAdd(Sg + 256 + pi, AxA);  atomicAdd(Sg + 256 + pi + 128, AxB);
        atomicAdd(Sg + 512 + pi, AyA);  atomicAdd(Sg + 512 + pi + 128, AyB);
        atomicAdd(Sg + 768 + pi, AzA);  atomicAdd(Sg + 768 + pi + 128, AzB);
    }
}

__global__ __launch_bounds__(256) void gmm_pass2(float* __restrict__ ws, int N)
{
    __shared__ double red6[6][4];
    const int c = threadIdx.x;
    const int lane = c & 63, wid = c >> 6;
    const float twok = ws[OFF_CF + 0];
    const double invt = 1.0 / (double)twok;
    double* CD = (double*)(ws + OFF_CD);

    float Sc  = ws[OFF_S       + c];
    float Axc = ws[OFF_S + 256 + c];
    float Ayc = ws[OFF_S + 512 + c];
    float Azc = ws[OFF_S + 768 + c];
    float4 p  = ((const float4*)(ws + OFF_P))[c];   // (twok*mu_old, alpha)

    float inv = 1.0f / fmaxf(Sc, 1e-37f);
    float mx = Axc * inv, my = Ayc * inv, mz = Azc * inv;   // mu_new (unscaled)
    ((float4*)(ws + OFF_Q))[c] = make_float4(mx, my, mz, 0.f);

    double v0 = (double)Sc;                                              // sumS
    double v1 = (double)Sc * (double)(mx*mx + my*my + mz*mz);            // S*||mu_new||^2
    double v2 = (double)Sc * log((double)fmaxf(Sc, 1e-37f));             // S*logS
    double v3 = (double)Sc * (double)(p.x*p.x + p.y*p.y + p.z*p.z);      // S*||twok*mu_old||^2
    double v4 = (double)Sc * (double)p.w;                                // S*alpha
    double v5 = (double)(p.x*Axc + p.y*Ayc + p.z*Azc);                   // (twok*mu_old) . A

    #pragma unroll
    for (int off = 32; off > 0; off >>= 1) {
        v0 += __shfl_xor(v0, off); v1 += __shfl_xor(v1, off); v2 += __shfl_xor(v2, off);
        v3 += __shfl_xor(v3, off); v4 += __shfl_xor(v4, off); v5 += __shfl_xor(v5, off);
    }
    if (lane == 0) { red6[0][wid]=v0; red6[1][wid]=v1; red6[2][wid]=v2;
                     red6[3][wid]=v3; red6[4][wid]=v4; red6[5][wid]=v5; }
    __syncthreads();
    if (c == 0) {
        double sumS   = red6[0][0]+red6[0][1]+red6[0][2]+red6[0][3];
        double sumSM2 = red6[1][0]+red6[1][1]+red6[1][2]+red6[1][3];
        double sumSlS = red6[2][0]+red6[2][1]+red6[2][2]+red6[2][3];
        double sumMSs = red6[3][0]+red6[3][1]+red6[3][2]+red6[3][3];   // scaled by twok^2
        double sumAS  = red6[4][0]+red6[4][1]+red6[4][2]+red6[4][3];
        double dotMAs = red6[5][0]+red6[5][1]+red6[5][2]+red6[5][3];   // scaled by twok
        double sumX2  = CD[0];
        double sumT2  = CD[1];
        double sumGD2 = sumX2 + sumMSs*invt*invt - 2.0 * dotMAs*invt;  // sum gamma*D2 (old mu)
        double sn2    = sumGD2 / (3.0 * (double)N);
        ws[OFF_CF + 2] = (float)(1.0 / (2.0 * sn2));
        ws[OFF_CF + 3] = (float)(sumSlS - sumS * log(sumS));  // sum S*lpi (ln units)
        ws[OFF_CF + 4] = (float)(sumAS + dotMAs - sumT2);     // sumGL2 (log2 units)
        CD[3] = sumSM2;
    }
}

__global__ __launch_bounds__(256, 4) void gmm_pass3(const float* __restrict__ X,
                                                    float* __restrict__ ws,
                                                    float* __restrict__ out, int N)
{
    __shared__ float4 Psh[CC], Qsh[CC];
    __shared__ float4 Yp[2][TILE];   // per-half partial Y per point
    __shared__ double redd[4];

    const int tid  = threadIdx.x;
    const int pi   = tid & 127;
    const int half = tid >> 7;
    const int n0   = blockIdx.x * TILE;
    const int NT   = min(TILE, N - n0);

    Psh[tid] = ((const float4*)(ws + OFF_P))[tid];
    Qsh[tid] = ((const float4*)(ws + OFF_Q))[tid];

    const bool v0 = pi < NT;
    float x0=0.f,y0=0.f,z0=0.f,T0=0.f;
    if (v0) { const float* p = X + 3*(size_t)(n0+pi); x0=p[0]; y0=p[1]; z0=p[2]; T0 = ws[OFF_T2+n0+pi]; }
    __syncthreads();

    // 1 point x 128 clusters per thread (half-split)
    const float4* Pc = Psh + half*128;
    const float4* Qc = Qsh + half*128;
    float Yx=0.f, Yy=0.f, Yz=0.f;
    #pragma unroll 8
    for (int c = 0; c < 128; ++c) {
        float4 p = Pc[c];
        float u = fmaf(x0,p.x, fmaf(y0,p.y, fmaf(z0,p.z, p.w)));
        float g = fexp2(u - T0);
        float4 q = Qc[c];
        Yx = fmaf(g,q.x,Yx); Yy = fmaf(g,q.y,Yy); Yz = fmaf(g,q.z,Yz);
    }
    Yp[half][pi] = make_float4(Yx, Yy, Yz, 0.f);
    __syncthreads();

    double y2d = 0.0;
    if (half == 0 && v0) {
        float4 a = Yp[0][pi], b = Yp[1][pi];
        float yx = a.x+b.x, yy = a.y+b.y, yz = a.z+b.z;
        float* op = out + 3*(size_t)(n0+pi);
        op[0]=yx; op[1]=yy; op[2]=yz;
        y2d = (double)yx*yx + (double)yy*yy + (double)yz*yz;
    }
    {
        const int lane = tid & 63, wid = tid >> 6;
        #pragma unroll
        for (int off = 32; off > 0; off >>= 1) y2d += __shfl_xor(y2d, off);
        if (lane == 0) redd[wid] = y2d;
    }
    __syncthreads();
    if (tid == 0) atomicAdd(((double*)(ws + OFF_CD)) + 2, redd[0]+redd[1]+redd[2]+redd[3]);
}

__global__ void gmm_pass4(float* __restrict__ ws, float* __restrict__ cfe_out, int N)
{
    if (threadIdx.x == 0) {
        double* CD = (double*)(ws + OFF_CD);
        double Cfe = (CD[3] - CD[2]) * (double)ws[OFF_CF + 2]
                   + (double)N * (double)ws[OFF_CF + 1]
                   + 0.69314718055994531 * (double)ws[OFF_CF + 4]
                   - (double)ws[OFF_CF + 3];
        cfe_out[0] = (float)Cfe;
    }
}

extern "C" void kernel_launch(void* const* d_in, const int* in_sizes, int n_in,
                              void* d_out, int out_size, void* d_ws, size_t ws_size,
                              hipStream_t stream)
{
    const float* X     = (const float*)d_in[0];
    const float* mu    = (const float*)d_in[1];
    const float* w     = (const float*)d_in[2];
    const float* sigma = (const float*)d_in[3];
    float* out = (float*)d_out;
    float* ws  = (float*)d_ws;
    const int N = in_sizes[0] / 3;
    const int nblk = (N + TILE - 1) / TILE;

    gmm_prep <<<1,    256, 0, stream>>>(mu, w, sigma, ws);
    gmm_pass1<<<nblk, 256, 0, stream>>>(X, ws, N);
    gmm_pass2<<<1,    256, 0, stream>>>(ws, N);
    gmm_pass3<<<nblk, 256, 0, stream>>>(X, ws, out, N);
    gmm_pass4<<<1,    64,  0, stream>>>(ws, out + (size_t)3 * N, N);
}

// Round 12
// 92.292 us; speedup vs baseline: 1.7169x; 1.7169x over previous
//
#include <hip/hip_runtime.h>
#include <math.h>

#define CC   256   // clusters
#define TILE 256   // points per block; 256 threads = 2 half-cluster groups x 128

// float-index offsets in ws
#define OFF_P     0        // 256 x float4: (twok*mu_x, twok*mu_y, twok*mu_z, alpha)
#define OFF_Q     1024     // (unused)
#define OFF_S     2048     // S[256] | Ax[256] | Ay[256] | Az[256]
#define OFF_CD    3072     // 4 doubles: [0]=sumX2 [1]=sumT2 [2]=sumY2 [3]=spare
#define OFF_CF    3080     // floats: [0]=twok [1]=lgn
#define OFF_T2    3088     // N floats: per-point log2-normalizer

__device__ __forceinline__ float fexp2(float x) { return __builtin_amdgcn_exp2f(x); }
__device__ __forceinline__ float flog2(float x) { return __builtin_amdgcn_logf(x); }  // v_log_f32 = log2

__global__ __launch_bounds__(256) void gmm_prep(const float* __restrict__ mu,
                                                const float* __restrict__ w,
                                                const float* __restrict__ sigma,
                                                float* __restrict__ ws)
{
    __shared__ float redA[4], redB[4];
    const int c = threadIdx.x;
    const int lane = c & 63, wid = c >> 6;

    // zero per-launch accumulators (stream-ordered before pass1)
    ws[OFF_S + c] = 0.f; ws[OFF_S + 256 + c] = 0.f;
    ws[OFF_S + 512 + c] = 0.f; ws[OFF_S + 768 + c] = 0.f;
    if (c < 4) ((double*)(ws + OFF_CD))[c] = 0.0;

    float wc = w[c];
    // Zw = logsumexp(w) over 256
    float m = wc;
    #pragma unroll
    for (int off = 32; off > 0; off >>= 1) m = fmaxf(m, __shfl_xor(m, off));
    if (lane == 0) redA[wid] = m;
    __syncthreads();
    m = fmaxf(fmaxf(redA[0], redA[1]), fmaxf(redA[2], redA[3]));
    float e = expf(wc - m);
    #pragma unroll
    for (int off = 32; off > 0; off >>= 1) e += __shfl_xor(e, off);
    if (lane == 0) redB[wid] = e;
    __syncthreads();
    float Zw = m + logf(redB[0] + redB[1] + redB[2] + redB[3]);

    const float L = 1.4426950408889634f;   // log2(e)
    float sig = sigma[0];
    float lgn = 3.0f * (logf(sig) + 0.91893853320467274f);  // d*(log sig + 0.5*log 2pi)
    float k = L / (2.0f * sig * sig);
    float twok = 2.0f * k;
    float mx = mu[3*c], my = mu[3*c+1], mz = mu[3*c+2];
    float m2 = mx*mx + my*my + mz*mz;
    float alpha = (wc - Zw - lgn) * L - k * m2;
    // pre-scaled: u_nc = x*P.x + y*P.y + z*P.z + P.w  (pure 3-fma chain)
    ((float4*)(ws + OFF_P))[c] = make_float4(twok*mx, twok*my, twok*mz, alpha);
    if (c == 0) { ws[OFF_CF + 0] = twok; ws[OFF_CF + 1] = lgn; }
}

__global__ __launch_bounds__(256, 4) void gmm_pass1(const float* __restrict__ X,
                                                    float* __restrict__ ws, int N)
{
    __shared__ float4 Psh[CC];
    __shared__ float4 XT[TILE];        // (x,y,z,T2) for phase B
    __shared__ float2 msP[2][TILE];    // per-half (m,s) partials per point
    __shared__ float4 Bpart[CC];       // half1 phase-B partials per cluster
    __shared__ double redd[2][4];

    const int tid  = threadIdx.x;
    const int pi   = tid & 127;
    const int half = tid >> 7;
    const int n0   = blockIdx.x * TILE;
    const int NT   = min(TILE, N - n0);

    Psh[tid] = ((const float4*)(ws + OFF_P))[tid];

    // two register-resident points per thread (same two points for both halves)
    const int i0 = pi, i1 = pi + 128;
    const bool v0 = i0 < NT, v1 = i1 < NT;
    float x0=0.f,y0=0.f,z0=0.f, x1=0.f,y1=0.f,z1=0.f;
    if (v0) { const float* p = X + 3*(size_t)(n0+i0); x0=p[0]; y0=p[1]; z0=p[2]; }
    if (v1) { const float* p = X + 3*(size_t)(n0+i1); x1=p[0]; y1=p[1]; z1=p[2]; }
    float q0 = fmaf(x0,x0, fmaf(y0,y0, z0*z0));
    float q1 = fmaf(x1,x1, fmaf(y1,y1, z1*z1));
    __syncthreads();   // Psh ready

    // phase A: 2 points x 128 clusters per thread (half-split), online LSE
    // chunk-16 deferred-max: branch-free u/max batch, ONE rescale check per chunk
    const float4* Pc = Psh + half*128;
    float m0=-3.0e38f, m1=-3.0e38f;
    float s0a=0.f, s0b=0.f, s1a=0.f, s1b=0.f;
    for (int c0 = 0; c0 < 128; c0 += 16) {
        float u0[16], u1[16];
        #pragma unroll
        for (int j = 0; j < 16; ++j) {
            float4 p = Pc[c0 + j];
            u0[j] = fmaf(x0,p.x, fmaf(y0,p.y, fmaf(z0,p.z, p.w)));
            u1[j] = fmaf(x1,p.x, fmaf(y1,p.y, fmaf(z1,p.z, p.w)));
        }
        float M0, M1;
        {
            float a = fmaxf(fmaxf(u0[0],u0[1]), fmaxf(u0[2],u0[3]));
            float b = fmaxf(fmaxf(u0[4],u0[5]), fmaxf(u0[6],u0[7]));
            float c = fmaxf(fmaxf(u0[8],u0[9]), fmaxf(u0[10],u0[11]));
            float d = fmaxf(fmaxf(u0[12],u0[13]), fmaxf(u0[14],u0[15]));
            M0 = fmaxf(fmaxf(a,b), fmaxf(c,d));
            a = fmaxf(fmaxf(u1[0],u1[1]), fmaxf(u1[2],u1[3]));
            b = fmaxf(fmaxf(u1[4],u1[5]), fmaxf(u1[6],u1[7]));
            c = fmaxf(fmaxf(u1[8],u1[9]), fmaxf(u1[10],u1[11]));
            d = fmaxf(fmaxf(u1[12],u1[13]), fmaxf(u1[14],u1[15]));
            M1 = fmaxf(fmaxf(a,b), fmaxf(c,d));
        }
        if (__any((M0 > m0) || (M1 > m1))) {     // at most once per chunk
            M0 = fmaxf(M0, m0); M1 = fmaxf(M1, m1);
            float r0 = fexp2(m0 - M0), r1 = fexp2(m1 - M1);
            s0a *= r0; s0b *= r0; s1a *= r1; s1b *= r1;
            m0 = M0; m1 = M1;
        }
        #pragma unroll
        for (int j = 0; j < 16; j += 2) {
            s0a += fexp2(u0[j]   - m0);
            s0b += fexp2(u0[j+1] - m0);
            s1a += fexp2(u1[j]   - m1);
            s1b += fexp2(u1[j+1] - m1);
        }
    }
    msP[half][i0] = make_float2(m0, s0a + s0b);
    msP[half][i1] = make_float2(m1, s1a + s1b);
    __syncthreads();   // msP ready

    // merge halves -> T2; write XT; accumulate sumX2/sumT2 (half0 only)
    double xd = 0.0, td = 0.0;
    if (half == 0) {
        if (v0) {
            float2 a = msP[0][i0], b = msP[1][i0];
            float M = fmaxf(a.x, b.x);
            float T2 = M + flog2(a.y*fexp2(a.x-M) + b.y*fexp2(b.x-M));
            XT[i0] = make_float4(x0,y0,z0,T2);
            ws[OFF_T2 + n0 + i0] = T2;
            xd += (double)q0; td += (double)T2;
        }
        if (v1) {
            float2 a = msP[0][i1], b = msP[1][i1];
            float M = fmaxf(a.x, b.x);
            float T2 = M + flog2(a.y*fexp2(a.x-M) + b.y*fexp2(b.x-M));
            XT[i1] = make_float4(x1,y1,z1,T2);
            ws[OFF_T2 + n0 + i1] = T2;
            xd += (double)q1; td += (double)T2;
        }
    }
    {
        const int lane = tid & 63, wid = tid >> 6;
        #pragma unroll
        for (int off = 32; off > 0; off >>= 1) { xd += __shfl_xor(xd, off); td += __shfl_xor(td, off); }
        if (lane == 0) { redd[0][wid] = xd; redd[1][wid] = td; }
    }
    __syncthreads();   // XT + redd ready
    if (tid == 0) {
        double* CD = (double*)(ws + OFF_CD);
        atomicAdd(CD + 0, redd[0][0]+redd[0][1]+redd[0][2]+redd[0][3]);
        atomicAdd(CD + 1, redd[1][0]+redd[1][1]+redd[1][2]+redd[1][3]);
    }

    // phase B: 2 clusters per thread over this half's 128 points
    float4 pA = Psh[pi], pB = Psh[pi + 128];
    float SA=0.f,AxA=0.f,AyA=0.f,AzA=0.f, SB=0.f,AxB=0.f,AyB=0.f,AzB=0.f;
    const int nlo = half*128, nhi = min(nlo+128, NT);
    #pragma unroll 8
    for (int n = nlo; n < nhi; ++n) {
        float4 xt = XT[n];
        float uA = fmaf(xt.x,pA.x, fmaf(xt.y,pA.y, fmaf(xt.z,pA.z, pA.w)));
        float uB = fmaf(xt.x,pB.x, fmaf(xt.y,pB.y, fmaf(xt.z,pB.z, pB.w)));
        float gA = fexp2(uA - xt.w);
        float gB = fexp2(uB - xt.w);
        SA+=gA; AxA=fmaf(gA,xt.x,AxA); AyA=fmaf(gA,xt.y,AyA); AzA=fmaf(gA,xt.z,AzA);
        SB+=gB; AxB=fmaf(gB,xt.x,AxB); AyB=fmaf(gB,xt.y,AyB); AzB=fmaf(gB,xt.z,AzB);
    }
    if (half == 1) {
        Bpart[pi]       = make_float4(SA,AxA,AyA,AzA);
        Bpart[pi + 128] = make_float4(SB,AxB,AyB,AzB);
    }
    __syncthreads();   // Bpart ready
    if (half == 0) {
        float4 bA = Bpart[pi], bB = Bpart[pi + 128];
        SA+=bA.x; AxA+=bA.y; AyA+=bA.z; AzA+=bA.w;
        SB+=bB.x; AxB+=bB.y; AyB+=bB.z; AzB+=bB.w;
        float* Sg = ws + OFF_S;
        atomicAdd(Sg       + pi, SA);   atomicAdd(Sg       + pi + 128, SB);
        atomicAdd(Sg + 256 + pi, AxA);  atomicAdd(Sg + 256 + pi + 128, AxB);
        atomicAdd(Sg + 512 + pi, AyA);  atomicAdd(Sg + 512 + pi + 128, AyB);
        atomicAdd(Sg + 768 + pi, AzA);  atomicAdd(Sg + 768 + pi + 128, AzB);
    }
}

__global__ __launch_bounds__(256) void gmm_pass3(const float* __restrict__ X,
                                                 float* __restrict__ ws,
                                                 float* __restrict__ out, int N)
{
    __shared__ float4 Psh[CC], Qsh[CC];
    __shared__ float4 Yp[2][TILE];   // per-half partial Y per point
    __shared__ double redd[4];

    const int tid  = threadIdx.x;
    const int pi   = tid & 127;
    const int half = tid >> 7;
    const int n0   = blockIdx.x * TILE;
    const int NT   = min(TILE, N - n0);

    Psh[tid] = ((const float4*)(ws + OFF_P))[tid];
    {   // per-block Q = A / S (replaces the old pass2 kernel's Q table)
        float Sc  = ws[OFF_S       + tid];
        float Axc = ws[OFF_S + 256 + tid];
        float Ayc = ws[OFF_S + 512 + tid];
        float Azc = ws[OFF_S + 768 + tid];
        float inv = 1.0f / fmaxf(Sc, 1e-37f);
        Qsh[tid] = make_float4(Axc*inv, Ayc*inv, Azc*inv, 0.f);
    }

    const int i0 = pi, i1 = pi + 128;
    const bool v0 = i0 < NT, v1 = i1 < NT;
    float x0=0.f,y0=0.f,z0=0.f,T0=0.f, x1=0.f,y1=0.f,z1=0.f,T1=0.f;
    if (v0) { const float* p = X + 3*(size_t)(n0+i0); x0=p[0]; y0=p[1]; z0=p[2]; T0 = ws[OFF_T2+n0+i0]; }
    if (v1) { const float* p = X + 3*(size_t)(n0+i1); x1=p[0]; y1=p[1]; z1=p[2]; T1 = ws[OFF_T2+n0+i1]; }
    __syncthreads();

    // 2 points x 128 clusters per thread (half-split)
    const float4* Pc = Psh + half*128;
    const float4* Qc = Qsh + half*128;
    float Yx0=0.f,Yy0=0.f,Yz0=0.f, Yx1=0.f,Yy1=0.f,Yz1=0.f;
    #pragma unroll 8
    for (int c = 0; c < 128; ++c) {
        float4 p = Pc[c];
        float u0 = fmaf(x0,p.x, fmaf(y0,p.y, fmaf(z0,p.z, p.w)));
        float u1 = fmaf(x1,p.x, fmaf(y1,p.y, fmaf(z1,p.z, p.w)));
        float g0 = fexp2(u0 - T0);
        float g1 = fexp2(u1 - T1);
        float4 q = Qc[c];
        Yx0 = fmaf(g0,q.x,Yx0); Yy0 = fmaf(g0,q.y,Yy0); Yz0 = fmaf(g0,q.z,Yz0);
        Yx1 = fmaf(g1,q.x,Yx1); Yy1 = fmaf(g1,q.y,Yy1); Yz1 = fmaf(g1,q.z,Yz1);
    }
    Yp[half][i0] = make_float4(Yx0,Yy0,Yz0,0.f);
    Yp[half][i1] = make_float4(Yx1,Yy1,Yz1,0.f);
    __syncthreads();

    double y2d = 0.0;
    if (half == 0) {
        if (v0) {
            float4 a = Yp[0][i0], b = Yp[1][i0];
            float yx = a.x+b.x, yy = a.y+b.y, yz = a.z+b.z;
            float* op = out + 3*(size_t)(n0+i0);
            op[0]=yx; op[1]=yy; op[2]=yz;
            y2d += (double)yx*yx + (double)yy*yy + (double)yz*yz;
        }
        if (v1) {
            float4 a = Yp[0][i1], b = Yp[1][i1];
            float yx = a.x+b.x, yy = a.y+b.y, yz = a.z+b.z;
            float* op = out + 3*(size_t)(n0+i1);
            op[0]=yx; op[1]=yy; op[2]=yz;
            y2d += (double)yx*yx + (double)yy*yy + (double)yz*yz;
        }
    }
    {
        const int lane = tid & 63, wid = tid >> 6;
        #pragma unroll
        for (int off = 32; off > 0; off >>= 1) y2d += __shfl_xor(y2d, off);
        if (lane == 0) redd[wid] = y2d;
    }
    __syncthreads();
    if (tid == 0) atomicAdd(((double*)(ws + OFF_CD)) + 2, redd[0]+redd[1]+redd[2]+redd[3]);
}

// merged old pass2 reductions + final Cfe (runs after pass3)
__global__ __launch_bounds__(256) void gmm_pass4(float* __restrict__ ws,
                                                 float* __restrict__ cfe_out, int N)
{
    __shared__ double red6[6][4];
    const int c = threadIdx.x;
    const int lane = c & 63, wid = c >> 6;
    const float twok = ws[OFF_CF + 0];
    const double invt = 1.0 / (double)twok;
    double* CD = (double*)(ws + OFF_CD);

    float Sc  = ws[OFF_S       + c];
    float Axc = ws[OFF_S + 256 + c];
    float Ayc = ws[OFF_S + 512 + c];
    float Azc = ws[OFF_S + 768 + c];
    float4 p  = ((const float4*)(ws + OFF_P))[c];   // (twok*mu_old, alpha)

    float inv = 1.0f / fmaxf(Sc, 1e-37f);
    float mx = Axc * inv, my = Ayc * inv, mz = Azc * inv;   // mu_new (unscaled)

    double v0 = (double)Sc;                                              // sumS
    double v1 = (double)Sc * (double)(mx*mx + my*my + mz*mz);            // S*||mu_new||^2
    double v2 = (double)Sc * log((double)fmaxf(Sc, 1e-37f));             // S*logS
    double v3 = (double)Sc * (double)(p.x*p.x + p.y*p.y + p.z*p.z);      // S*||twok*mu_old||^2
    double v4 = (double)Sc * (double)p.w;                                // S*alpha
    double v5 = (double)(p.x*Axc + p.y*Ayc + p.z*Azc);                   // (twok*mu_old) . A

    #pragma unroll
    for (int off = 32; off > 0; off >>= 1) {
        v0 += __shfl_xor(v0, off); v1 += __shfl_xor(v1, off); v2 += __shfl_xor(v2, off);
        v3 += __shfl_xor(v3, off); v4 += __shfl_xor(v4, off); v5 += __shfl_xor(v5, off);
    }
    if (lane == 0) { red6[0][wid]=v0; red6[1][wid]=v1; red6[2][wid]=v2;
                     red6[3][wid]=v3; red6[4][wid]=v4; red6[5][wid]=v5; }
    __syncthreads();
    if (c == 0) {
        double sumS   = red6[0][0]+red6[0][1]+red6[0][2]+red6[0][3];
        double sumSM2 = red6[1][0]+red6[1][1]+red6[1][2]+red6[1][3];
        double sumSlS = red6[2][0]+red6[2][1]+red6[2][2]+red6[2][3];
        double sumMSs = red6[3][0]+red6[3][1]+red6[3][2]+red6[3][3];   // scaled by twok^2
        double sumAS  = red6[4][0]+red6[4][1]+red6[4][2]+red6[4][3];
        double dotMAs = red6[5][0]+red6[5][1]+red6[5][2]+red6[5][3];   // scaled by twok
        double sumX2  = CD[0];
        double sumT2  = CD[1];
        double sumY2  = CD[2];
        double sumGD2 = sumX2 + sumMSs*invt*invt - 2.0 * dotMAs*invt;  // sum gamma*D2 (old mu)
        double sn2    = sumGD2 / (3.0 * (double)N);
        double sumSlpi = sumSlS - sumS * log(sumS);                    // ln units
        double sumGL2  = sumAS + dotMAs - sumT2;                       // log2 units
        double lgn     = (double)ws[OFF_CF + 1];
        double Cfe = (sumSM2 - sumY2) / (2.0 * sn2)
                   + (double)N * lgn
                   + 0.69314718055994531 * sumGL2
                   - sumSlpi;
        cfe_out[0] = (float)Cfe;
    }
}

extern "C" void kernel_launch(void* const* d_in, const int* in_sizes, int n_in,
                              void* d_out, int out_size, void* d_ws, size_t ws_size,
                              hipStream_t stream)
{
    const float* X     = (const float*)d_in[0];
    const float* mu    = (const float*)d_in[1];
    const float* w     = (const float*)d_in[2];
    const float* sigma = (const float*)d_in[3];
    float* out = (float*)d_out;
    float* ws  = (float*)d_ws;
    const int N = in_sizes[0] / 3;
    const int nblk = (N + TILE - 1) / TILE;

    gmm_prep <<<1,    256, 0, stream>>>(mu, w, sigma, ws);
    gmm_pass1<<<nblk, 256, 0, stream>>>(X, ws, N);
    gmm_pass3<<<nblk, 256, 0, stream>>>(X, ws, out, N);
    gmm_pass4<<<1,    256, 0, stream>>>(ws, out + (size_t)3 * N, N);
}